// Round 1
// baseline (138.399 us; speedup 1.0000x reference)
//
#include <hip/hip_runtime.h>
#include <hip/hip_bf16.h>

typedef __bf16 bf16;
typedef __attribute__((ext_vector_type(4))) __bf16 bf16x4;
typedef __attribute__((ext_vector_type(8))) __bf16 bf16x8;
typedef __attribute__((ext_vector_type(4))) float f32x4;

#define T_SEQ 4096
#define D_EMB 1024
#define HS 64

__device__ __forceinline__ float fexp2(float x) {
#if __has_builtin(__builtin_amdgcn_exp2f)
    return __builtin_amdgcn_exp2f(x);
#else
    return exp2f(x);
#endif
}

// ---------------------------------------------------------------------------
// Kernel 0: cast Wk|Wv (fp32, 64x1024 each) -> bf16 workspace copies.
// ---------------------------------------------------------------------------
__global__ __launch_bounds__(256) void wcast_kernel(
    const float* __restrict__ Wk, const float* __restrict__ Wv,
    bf16* __restrict__ wbf)   // [128][1024]
{
    const int t = blockIdx.x * 256 + threadIdx.x;
    const int base = t * 8;
    const float* src = (base < 65536) ? (Wk + base) : (Wv + base - 65536);
    float4 f0 = *(const float4*)(src);
    float4 f1 = *(const float4*)(src + 4);
    bf16x8 o = {(__bf16)f0.x, (__bf16)f0.y, (__bf16)f0.z, (__bf16)f0.w,
                (__bf16)f1.x, (__bf16)f1.y, (__bf16)f1.z, (__bf16)f1.w};
    *(bf16x8*)(wbf + base) = o;
}

// ---------------------------------------------------------------------------
// Kernel 1: staged-LDS projection GEMM, BM=32, full N=128, no split-K.
// Grid 512 = 2 blocks/CU. Single-buffer LDS (23 KB) + register prefetch,
// 2-barrier chunk loop; cross-block TLP hides the barrier drains.
// Direct bf16 epilogue; qvT built via in-LDS transpose -> coalesced stores.
// ---------------------------------------------------------------------------
__global__ __launch_bounds__(256, 2) void proj_kernel(
    const float* __restrict__ x,    // [16384][1024] fp32
    const bf16* __restrict__ wbf,   // [128][1024] bf16 (Wk rows 0-63, Wv 64-127)
    bf16* __restrict__ kmat,        // [16384][64]
    bf16* __restrict__ qvmat,       // [16384][64]
    bf16* __restrict__ qvT)         // [4][64][4096]
{
    __shared__ bf16 xs[32][72];     // 4.6 KB  (rows padded to 144 B)
    __shared__ bf16 wsh[128][72];   // 18.4 KB
    __shared__ bf16 vt[64][40];     // 5 KB    (qv transpose tile, 80 B rows)

    const int tid  = threadIdx.x;
    const int lane = tid & 63;
    const int wave = tid >> 6;
    const int col  = lane & 15;
    const int quad = lane >> 4;
    const int rowbase = blockIdx.x * 32;

    f32x4 acc[2][2];
#pragma unroll
    for (int mt = 0; mt < 2; ++mt)
#pragma unroll
        for (int nt = 0; nt < 2; ++nt) acc[mt][nt] = {0.f, 0.f, 0.f, 0.f};

    // register prefetch of chunk 0
    float4 xn[2];
    bf16x8 wn[4];
    {
#pragma unroll
        for (int p = 0; p < 2; ++p) {
            const int idx = p * 256 + tid;          // 512 float4s: x 32x64
            const int xr  = idx >> 4;
            const int c4  = (idx & 15) * 4;
            xn[p] = *(const float4*)(x + (size_t)(rowbase + xr) * D_EMB + c4);
        }
#pragma unroll
        for (int p = 0; p < 4; ++p) {
            const int idx = p * 256 + tid;          // 1024 bf16x8s: W 128x64
            const int wr  = idx >> 3;
            const int off = (idx & 7) * 8;
            wn[p] = *(const bf16x8*)(wbf + (size_t)wr * D_EMB + off);
        }
    }

#pragma unroll 1
    for (int c = 0; c < 16; ++c) {
        // ---- write prefetched chunk into LDS ----
#pragma unroll
        for (int p = 0; p < 2; ++p) {
            const int idx = p * 256 + tid;
            const int xr  = idx >> 4;
            const int c4  = (idx & 15) * 4;
            bf16x4 v = {(__bf16)xn[p].x, (__bf16)xn[p].y,
                        (__bf16)xn[p].z, (__bf16)xn[p].w};
            *(bf16x4*)&xs[xr][c4] = v;
        }
#pragma unroll
        for (int p = 0; p < 4; ++p) {
            const int idx = p * 256 + tid;
            const int wr  = idx >> 3;
            const int off = (idx & 7) * 8;
            *(bf16x8*)&wsh[wr][off] = wn[p];
        }
        __syncthreads();

        // ---- issue next chunk's loads (hidden behind compute) ----
        if (c < 15) {
            const int k0 = (c + 1) * 64;
#pragma unroll
            for (int p = 0; p < 2; ++p) {
                const int idx = p * 256 + tid;
                const int xr  = idx >> 4;
                const int c4  = (idx & 15) * 4;
                xn[p] = *(const float4*)(x + (size_t)(rowbase + xr) * D_EMB + k0 + c4);
            }
#pragma unroll
            for (int p = 0; p < 4; ++p) {
                const int idx = p * 256 + tid;
                const int wr  = idx >> 3;
                const int off = (idx & 7) * 8;
                wn[p] = *(const bf16x8*)(wbf + (size_t)wr * D_EMB + k0 + off);
            }
        }

        // ---- compute chunk from LDS ----
#pragma unroll
        for (int s = 0; s < 2; ++s) {
            bf16x8 af[2];
#pragma unroll
            for (int mt = 0; mt < 2; ++mt)
                af[mt] = *(const bf16x8*)&xs[mt * 16 + col][s * 32 + quad * 8];
            bf16x8 bfr[2];
#pragma unroll
            for (int nt = 0; nt < 2; ++nt)
                bfr[nt] = *(const bf16x8*)&wsh[wave * 32 + nt * 16 + col][s * 32 + quad * 8];
#pragma unroll
            for (int mt = 0; mt < 2; ++mt)
#pragma unroll
                for (int nt = 0; nt < 2; ++nt)
                    acc[mt][nt] = __builtin_amdgcn_mfma_f32_16x16x32_bf16(
                        af[mt], bfr[nt], acc[mt][nt], 0, 0, 0);
        }
        __syncthreads();
    }

    // ---- epilogue: C layout col=lane&15, row=quad*4+reg ----
    // waves 0,1 own kmat cols 0..63; waves 2,3 own qvmat cols 0..63.
#pragma unroll
    for (int mt = 0; mt < 2; ++mt)
#pragma unroll
        for (int nt = 0; nt < 2; ++nt) {
            const int gcol = wave * 32 + nt * 16 + col;
#pragma unroll
            for (int r = 0; r < 4; ++r) {
                const int grow = rowbase + mt * 16 + quad * 4 + r;
                const int ltt  = mt * 16 + quad * 4 + r;
                bf16 bv = (bf16)acc[mt][nt][r];
                if (gcol < 64) {
                    kmat[(size_t)grow * HS + gcol] = bv;
                } else {
                    qvmat[(size_t)grow * HS + (gcol - 64)] = bv;
                    vt[gcol - 64][ltt] = bv;     // transpose tile in LDS
                }
            }
        }
    __syncthreads();

    // qvT store: thread -> (h = tid>>2, 8-elem segment), 16 B coalesced rows
    {
        const int h   = tid >> 2;
        const int seg = (tid & 3) * 8;
        bf16x8 v = *(const bf16x8*)&vt[h][seg];
        const int bb  = rowbase >> 12;
        const int tt0 = (rowbase & (T_SEQ - 1)) + seg;
        *(bf16x8*)(qvT + ((size_t)bb * HS + h) * T_SEQ + tt0) = v;
    }
}

// ---------------------------------------------------------------------------
// Kernel 2: staged-LDS causal attention, fixed-offset softmax, q = v.
// Single-buffered LDS (23.4 KB) + register prefetch across the chunk barrier.
// launch_bounds(256,4): 4 blocks/CU at VGPR<=128 (no spill). Heavy jobs
// dispatch first. Partial (O, l) per job slot; norm combines.
// ---------------------------------------------------------------------------
__global__ __launch_bounds__(256, 4) void attn_kernel(
    const bf16* __restrict__ kmat,   // [B*T][64]
    const bf16* __restrict__ qvmat,  // [B*T][64]
    const bf16* __restrict__ qvT,    // [B][64][T]
    float* __restrict__ out,         // [B*T][64] raw O partial, slot 0
    float* __restrict__ o_parts,     // [7][B*T][64] raw O partials, slots 1-7
    float* __restrict__ l_parts)     // [8][B*T] l partials
{
    __shared__ bf16 Kt[64][72];      // 9.2 KB
    __shared__ bf16 Vt[64][72];      // 9.2 KB
    __shared__ bf16 plds[4][16][40]; // 5 KB

    const int tid  = threadIdx.x;
    const int lane = tid & 63;
    const int wave = tid >> 6;
    const int col  = lane & 15;
    const int quad = lane >> 4;

    const int b = blockIdx.x / 288;
    const int r = 287 - (blockIdx.x - b * 288);   // heavy tiers first
    int a = 0;
    while (4 * (a + 1) * (a + 2) <= r) ++a;       // a in 0..7
    const int rr = r - 4 * a * (a + 1);
    const int m  = rr / (a + 1);
    const int jc = rr - m * (a + 1);              // job slot 0..a
    const int qb = 8 * a + m;                     // q-block 0..63

    const int cbeg  = jc * 8;
    const int nctot = qb + 1;
    const int cend  = (nctot < cbeg + 8) ? nctot : cbeg + 8;

    const bf16* qvb = qvmat + (size_t)b * T_SEQ * HS;
    const bf16* kb  = kmat  + (size_t)b * T_SEQ * HS;
    const bf16* vTb = qvT   + (size_t)b * HS * T_SEQ;

    const int q0 = qb * 64 + wave * 16;

    bf16x8 qf0 = *(const bf16x8*)(qvb + (size_t)(q0 + col) * HS + quad * 8);
    bf16x8 qf1 = *(const bf16x8*)(qvb + (size_t)(q0 + col) * HS + 32 + quad * 8);

    f32x4 o[4];
    float lp[4];
#pragma unroll
    for (int h = 0; h < 4; ++h) o[h] = {0.f, 0.f, 0.f, 0.f};
#pragma unroll
    for (int i = 0; i < 4; ++i) lp[i] = 0.f;

    const float sc = 0.125f * 1.44269504088896f;

    // register prefetch of first chunk
    bf16x8 kn[2], vn[2];
    {
        const int kc = cbeg * 64;
#pragma unroll
        for (int it = 0; it < 2; ++it) {
            const int idx = it * 256 + tid;
            const int kr  = idx >> 3;
            const int off = (idx & 7) * 8;
            kn[it] = *(const bf16x8*)(kb + (size_t)kc * HS + idx * 8);
            vn[it] = *(const bf16x8*)(vTb + (size_t)kr * T_SEQ + kc + off);
        }
    }

#pragma unroll 1
    for (int c = cbeg; c < cend; ++c) {
        // ---- write prefetched chunk into LDS ----
#pragma unroll
        for (int it = 0; it < 2; ++it) {
            const int idx = it * 256 + tid;
            const int kr  = idx >> 3;
            const int off = (idx & 7) * 8;
            *(bf16x8*)&Kt[kr][off] = kn[it];
            *(bf16x8*)&Vt[kr][off] = vn[it];
        }
        __syncthreads();

        // ---- issue next chunk's loads (hidden behind compute) ----
        if (c + 1 < cend) {
            const int kcn = (c + 1) * 64;
#pragma unroll
            for (int it = 0; it < 2; ++it) {
                const int idx = it * 256 + tid;
                const int kr  = idx >> 3;
                const int off = (idx & 7) * 8;
                kn[it] = *(const bf16x8*)(kb + (size_t)kcn * HS + idx * 8);
                vn[it] = *(const bf16x8*)(vTb + (size_t)kr * T_SEQ + kcn + off);
            }
        }

        // ---- compute chunk c from LDS ----
        const int kc = c * 64;
#pragma unroll
        for (int st = 0; st < 2; ++st) {
            const int gk = kc + 32 * st;
            if (gk > q0 + 15) break;             // fully masked (wave-uniform)

            bf16x8 b0 = *(const bf16x8*)&Kt[32 * st + col][quad * 8];
            bf16x8 b1 = *(const bf16x8*)&Kt[32 * st + col][32 + quad * 8];
            bf16x8 b2 = *(const bf16x8*)&Kt[32 * st + 16 + col][quad * 8];
            bf16x8 b3 = *(const bf16x8*)&Kt[32 * st + 16 + col][32 + quad * 8];

            float p[2][4];
            {
                f32x4 a4 = {0.f, 0.f, 0.f, 0.f};
                a4 = __builtin_amdgcn_mfma_f32_16x16x32_bf16(qf0, b0, a4, 0, 0, 0);
                a4 = __builtin_amdgcn_mfma_f32_16x16x32_bf16(qf1, b1, a4, 0, 0, 0);
#pragma unroll
                for (int i = 0; i < 4; ++i) p[0][i] = fexp2(fmaf(a4[i], sc, -24.f));
            }
            {
                f32x4 a4 = {0.f, 0.f, 0.f, 0.f};
                a4 = __builtin_amdgcn_mfma_f32_16x16x32_bf16(qf0, b2, a4, 0, 0, 0);
                a4 = __builtin_amdgcn_mfma_f32_16x16x32_bf16(qf1, b3, a4, 0, 0, 0);
#pragma unroll
                for (int i = 0; i < 4; ++i) p[1][i] = fexp2(fmaf(a4[i], sc, -24.f));
            }

            if (gk + 31 > q0) {                  // diagonal subtile: mask
#pragma unroll
                for (int nt = 0; nt < 2; ++nt)
#pragma unroll
                    for (int i = 0; i < 4; ++i)
                        if (gk + nt * 16 + col > q0 + quad * 4 + i)
                            p[nt][i] = 0.f;
            }

#pragma unroll
            for (int i = 0; i < 4; ++i) lp[i] += p[0][i] + p[1][i];

            // P: C-layout -> LDS -> A-layout (wave-private, in-order DS)
#pragma unroll
            for (int nt = 0; nt < 2; ++nt)
#pragma unroll
                for (int i = 0; i < 4; ++i)
                    plds[wave][quad * 4 + i][nt * 16 + col] = (bf16)p[nt][i];
            bf16x8 pa = *(const bf16x8*)&plds[wave][col][quad * 8];

#pragma unroll
            for (int h = 0; h < 4; ++h) {
                bf16x8 vb = *(const bf16x8*)&Vt[h * 16 + col][32 * st + quad * 8];
                o[h] = __builtin_amdgcn_mfma_f32_16x16x32_bf16(pa, vb, o[h], 0, 0, 0);
            }
        }
        __syncthreads();   // protect Kt/Vt before next write
    }

    // ---- epilogue: waves own disjoint rows -> direct partial stores ----
    float lr[4];
#pragma unroll
    for (int i = 0; i < 4; ++i) {
        float v = lp[i];
#pragma unroll
        for (int off = 1; off < 16; off <<= 1)
            v += __shfl_xor(v, off, 64);
        lr[i] = v;
    }

    const size_t rowbase = (size_t)b * T_SEQ + q0 + quad * 4;
    if (col == 0) {
#pragma unroll
        for (int i = 0; i < 4; ++i)
            l_parts[(size_t)jc * 16384 + rowbase + i] = lr[i];
    }

    float* dst = (jc == 0) ? out : (o_parts + (size_t)(jc - 1) * 16384 * HS);
#pragma unroll
    for (int h = 0; h < 4; ++h)
#pragma unroll
        for (int i = 0; i < 4; ++i)
            dst[(rowbase + i) * HS + h * 16 + col] = o[h][i];
}

// ---------------------------------------------------------------------------
// Kernel 3: combine job partials and normalize: out = sum(O_j) / sum(l_j).
// ---------------------------------------------------------------------------
__global__ __launch_bounds__(256) void norm_kernel(
    float* __restrict__ out,
    const float* __restrict__ o_parts,  // [7][B*T][64]
    const float* __restrict__ l_parts)  // [8][B*T]
{
    const int i   = blockIdx.x * 256 + threadIdx.x;
    const int row = i >> 6;
    const int qb  = (row & 4095) >> 6;
    const int nj  = (qb >> 3) + 1;

    float s = out[i];
    float L = l_parts[row];
    for (int j = 1; j < nj; ++j) {
        s += o_parts[(size_t)(j - 1) * 1048576 + i];
        L += l_parts[(size_t)j * 16384 + row];
    }
    out[i] = s / L;
}

extern "C" void kernel_launch(void* const* d_in, const int* in_sizes, int n_in,
                              void* d_out, int out_size, void* d_ws, size_t ws_size,
                              hipStream_t stream) {
    const float* x  = (const float*)d_in[0];
    const float* Wk = (const float*)d_in[1];
    const float* Wv = (const float*)d_in[2];
    float* out = (float*)d_out;

    bf16* ws    = (bf16*)d_ws;
    bf16* wbf   = ws;                                    // 256 KB
    bf16* kmat  = ws + (size_t)128 * 1024;               // 2 MB
    bf16* qvmat = kmat + (size_t)16384 * 64;             // 2 MB
    bf16* qvT   = qvmat + (size_t)16384 * 64;            // 2 MB
    float* o_parts = (float*)(qvT + (size_t)16384 * 64); // 28 MB (slots 1-7)
    float* l_parts = o_parts + (size_t)7 * 16384 * 64;   // 512 KB

    wcast_kernel<<<64, 256, 0, stream>>>(Wk, Wv, wbf);
    proj_kernel<<<512, 256, 0, stream>>>(x, wbf, kmat, qvmat, qvT);
    attn_kernel<<<1152, 256, 0, stream>>>(kmat, qvmat, qvT, out, o_parts, l_parts);
    norm_kernel<<<4096, 256, 0, stream>>>(out, o_parts, l_parts);
}

// Round 2
// 137.352 us; speedup vs baseline: 1.0076x; 1.0076x over previous
//
#include <hip/hip_runtime.h>
#include <hip/hip_bf16.h>

typedef __bf16 bf16;
typedef __attribute__((ext_vector_type(4))) __bf16 bf16x4;
typedef __attribute__((ext_vector_type(8))) __bf16 bf16x8;
typedef __attribute__((ext_vector_type(4))) float f32x4;
typedef __attribute__((ext_vector_type(4))) short s16x4;

#define T_SEQ 4096
#define D_EMB 1024
#define HS 64

#if __has_builtin(__builtin_amdgcn_mfma_f32_16x16x16bf16_1k)
#define MFMA16_OK 1
#else
#define MFMA16_OK 0
#endif

__device__ __forceinline__ float fexp2(float x) {
#if __has_builtin(__builtin_amdgcn_exp2f)
    return __builtin_amdgcn_exp2f(x);
#else
    return exp2f(x);
#endif
}

#if MFMA16_OK
__device__ __forceinline__ s16x4 bc4(bf16x4 v) {
    return __builtin_bit_cast(s16x4, v);
}
#endif

// ---------------------------------------------------------------------------
// Kernel 0: cast Wk|Wv (fp32, 64x1024 each) -> bf16 workspace copies.
// ---------------------------------------------------------------------------
__global__ __launch_bounds__(256) void wcast_kernel(
    const float* __restrict__ Wk, const float* __restrict__ Wv,
    bf16* __restrict__ wbf)   // [128][1024]
{
    const int t = blockIdx.x * 256 + threadIdx.x;
    const int base = t * 8;
    const float* src = (base < 65536) ? (Wk + base) : (Wv + base - 65536);
    float4 f0 = *(const float4*)(src);
    float4 f1 = *(const float4*)(src + 4);
    bf16x8 o = {(__bf16)f0.x, (__bf16)f0.y, (__bf16)f0.z, (__bf16)f0.w,
                (__bf16)f1.x, (__bf16)f1.y, (__bf16)f1.z, (__bf16)f1.w};
    *(bf16x8*)(wbf + base) = o;
}

// ---------------------------------------------------------------------------
// Kernel 1: staged-LDS projection GEMM, BM=32, full N=128, no split-K.
// (unchanged this round — isolating the attn change for attribution)
// ---------------------------------------------------------------------------
__global__ __launch_bounds__(256, 2) void proj_kernel(
    const float* __restrict__ x,    // [16384][1024] fp32
    const bf16* __restrict__ wbf,   // [128][1024] bf16 (Wk rows 0-63, Wv 64-127)
    bf16* __restrict__ kmat,        // [16384][64]
    bf16* __restrict__ qvmat,       // [16384][64]
    bf16* __restrict__ qvT)         // [4][64][4096]
{
    __shared__ bf16 xs[32][72];     // 4.6 KB  (rows padded to 144 B)
    __shared__ bf16 wsh[128][72];   // 18.4 KB
    __shared__ bf16 vt[64][40];     // 5 KB    (qv transpose tile, 80 B rows)

    const int tid  = threadIdx.x;
    const int lane = tid & 63;
    const int wave = tid >> 6;
    const int col  = lane & 15;
    const int quad = lane >> 4;
    const int rowbase = blockIdx.x * 32;

    f32x4 acc[2][2];
#pragma unroll
    for (int mt = 0; mt < 2; ++mt)
#pragma unroll
        for (int nt = 0; nt < 2; ++nt) acc[mt][nt] = {0.f, 0.f, 0.f, 0.f};

    // register prefetch of chunk 0
    float4 xn[2];
    bf16x8 wn[4];
    {
#pragma unroll
        for (int p = 0; p < 2; ++p) {
            const int idx = p * 256 + tid;          // 512 float4s: x 32x64
            const int xr  = idx >> 4;
            const int c4  = (idx & 15) * 4;
            xn[p] = *(const float4*)(x + (size_t)(rowbase + xr) * D_EMB + c4);
        }
#pragma unroll
        for (int p = 0; p < 4; ++p) {
            const int idx = p * 256 + tid;          // 1024 bf16x8s: W 128x64
            const int wr  = idx >> 3;
            const int off = (idx & 7) * 8;
            wn[p] = *(const bf16x8*)(wbf + (size_t)wr * D_EMB + off);
        }
    }

#pragma unroll 1
    for (int c = 0; c < 16; ++c) {
        // ---- write prefetched chunk into LDS ----
#pragma unroll
        for (int p = 0; p < 2; ++p) {
            const int idx = p * 256 + tid;
            const int xr  = idx >> 4;
            const int c4  = (idx & 15) * 4;
            bf16x4 v = {(__bf16)xn[p].x, (__bf16)xn[p].y,
                        (__bf16)xn[p].z, (__bf16)xn[p].w};
            *(bf16x4*)&xs[xr][c4] = v;
        }
#pragma unroll
        for (int p = 0; p < 4; ++p) {
            const int idx = p * 256 + tid;
            const int wr  = idx >> 3;
            const int off = (idx & 7) * 8;
            *(bf16x8*)&wsh[wr][off] = wn[p];
        }
        __syncthreads();

        // ---- issue next chunk's loads (hidden behind compute) ----
        if (c < 15) {
            const int k0 = (c + 1) * 64;
#pragma unroll
            for (int p = 0; p < 2; ++p) {
                const int idx = p * 256 + tid;
                const int xr  = idx >> 4;
                const int c4  = (idx & 15) * 4;
                xn[p] = *(const float4*)(x + (size_t)(rowbase + xr) * D_EMB + k0 + c4);
            }
#pragma unroll
            for (int p = 0; p < 4; ++p) {
                const int idx = p * 256 + tid;
                const int wr  = idx >> 3;
                const int off = (idx & 7) * 8;
                wn[p] = *(const bf16x8*)(wbf + (size_t)wr * D_EMB + k0 + off);
            }
        }

        // ---- compute chunk from LDS ----
#pragma unroll
        for (int s = 0; s < 2; ++s) {
            bf16x8 af[2];
#pragma unroll
            for (int mt = 0; mt < 2; ++mt)
                af[mt] = *(const bf16x8*)&xs[mt * 16 + col][s * 32 + quad * 8];
            bf16x8 bfr[2];
#pragma unroll
            for (int nt = 0; nt < 2; ++nt)
                bfr[nt] = *(const bf16x8*)&wsh[wave * 32 + nt * 16 + col][s * 32 + quad * 8];
#pragma unroll
            for (int mt = 0; mt < 2; ++mt)
#pragma unroll
                for (int nt = 0; nt < 2; ++nt)
                    acc[mt][nt] = __builtin_amdgcn_mfma_f32_16x16x32_bf16(
                        af[mt], bfr[nt], acc[mt][nt], 0, 0, 0);
        }
        __syncthreads();
    }

    // ---- epilogue: C layout col=lane&15, row=quad*4+reg ----
#pragma unroll
    for (int mt = 0; mt < 2; ++mt)
#pragma unroll
        for (int nt = 0; nt < 2; ++nt) {
            const int gcol = wave * 32 + nt * 16 + col;
#pragma unroll
            for (int r = 0; r < 4; ++r) {
                const int grow = rowbase + mt * 16 + quad * 4 + r;
                const int ltt  = mt * 16 + quad * 4 + r;
                bf16 bv = (bf16)acc[mt][nt][r];
                if (gcol < 64) {
                    kmat[(size_t)grow * HS + gcol] = bv;
                } else {
                    qvmat[(size_t)grow * HS + (gcol - 64)] = bv;
                    vt[gcol - 64][ltt] = bv;     // transpose tile in LDS
                }
            }
        }
    __syncthreads();

    // qvT store: thread -> (h = tid>>2, 8-elem segment), 16 B coalesced rows
    {
        const int h   = tid >> 2;
        const int seg = (tid & 3) * 8;
        bf16x8 v = *(const bf16x8*)&vt[h][seg];
        const int bb  = rowbase >> 12;
        const int tt0 = (rowbase & (T_SEQ - 1)) + seg;
        *(bf16x8*)(qvT + ((size_t)bb * HS + h) * T_SEQ + tt0) = v;
    }
}

// ---------------------------------------------------------------------------
// Kernel 2: staged-LDS causal attention, SWAPPED QK^T (S^T = K·Q^T) so P is
// lane-local per q-row. PV consumes P directly from registers via
// mfma_f32_16x16x16bf16_1k (A-frag k=quad*4+j matches S^T output layout) —
// the P LDS round-trip (8x ds_write_b16 + ds_read_b128 + wait) is GONE.
// Fallback (no _1k builtin): plds with vectorized b64 writes + 16x16x32 PV.
// ---------------------------------------------------------------------------
__global__ __launch_bounds__(256, 4) void attn_kernel(
    const bf16* __restrict__ kmat,   // [B*T][64]
    const bf16* __restrict__ qvmat,  // [B*T][64]
    const bf16* __restrict__ qvT,    // [B][64][T]
    float* __restrict__ out,         // [B*T][64] raw O partial, slot 0
    float* __restrict__ o_parts,     // [7][B*T][64] raw O partials, slots 1-7
    float* __restrict__ l_parts)     // [8][B*T] l partials
{
    __shared__ bf16 Kt[64][72];      // 9.2 KB
    __shared__ bf16 Vt[64][72];      // 9.2 KB
#if !MFMA16_OK
    __shared__ bf16 plds[4][16][40]; // fallback P staging (80 B rows, 16B-aligned)
#endif

    const int tid  = threadIdx.x;
    const int lane = tid & 63;
    const int wave = tid >> 6;
    const int col  = lane & 15;
    const int quad = lane >> 4;

    const int b = blockIdx.x / 288;
    const int r = 287 - (blockIdx.x - b * 288);   // heavy tiers first
    int a = 0;
    while (4 * (a + 1) * (a + 2) <= r) ++a;       // a in 0..7
    const int rr = r - 4 * a * (a + 1);
    const int m  = rr / (a + 1);
    const int jc = rr - m * (a + 1);              // job slot 0..a
    const int qb = 8 * a + m;                     // q-block 0..63

    const int cbeg  = jc * 8;
    const int nctot = qb + 1;
    const int cend  = (nctot < cbeg + 8) ? nctot : cbeg + 8;

    const bf16* qvb = qvmat + (size_t)b * T_SEQ * HS;
    const bf16* kb  = kmat  + (size_t)b * T_SEQ * HS;
    const bf16* vTb = qvT   + (size_t)b * HS * T_SEQ;

    const int q0 = qb * 64 + wave * 16;

    // Q fragment: Q[q0+col][d=quad*8+j] — serves as MFMA B-operand (col=lane&15)
    bf16x8 qf0 = *(const bf16x8*)(qvb + (size_t)(q0 + col) * HS + quad * 8);
    bf16x8 qf1 = *(const bf16x8*)(qvb + (size_t)(q0 + col) * HS + 32 + quad * 8);

    f32x4 o[4];
#pragma unroll
    for (int h = 0; h < 4; ++h) o[h] = {0.f, 0.f, 0.f, 0.f};
    float lsum = 0.f;

    const float sc = 0.125f * 1.44269504088896f;

    // register prefetch of first chunk
    bf16x8 kn[2], vn[2];
    {
        const int kc = cbeg * 64;
#pragma unroll
        for (int it = 0; it < 2; ++it) {
            const int idx = it * 256 + tid;
            const int kr  = idx >> 3;
            const int off = (idx & 7) * 8;
            kn[it] = *(const bf16x8*)(kb + (size_t)kc * HS + idx * 8);
            vn[it] = *(const bf16x8*)(vTb + (size_t)kr * T_SEQ + kc + off);
        }
    }

#pragma unroll 1
    for (int c = cbeg; c < cend; ++c) {
        // ---- write prefetched chunk into LDS ----
#pragma unroll
        for (int it = 0; it < 2; ++it) {
            const int idx = it * 256 + tid;
            const int kr  = idx >> 3;
            const int off = (idx & 7) * 8;
            *(bf16x8*)&Kt[kr][off] = kn[it];
            *(bf16x8*)&Vt[kr][off] = vn[it];
        }
        __syncthreads();

        // ---- issue next chunk's loads (hidden behind compute) ----
        if (c + 1 < cend) {
            const int kcn = (c + 1) * 64;
#pragma unroll
            for (int it = 0; it < 2; ++it) {
                const int idx = it * 256 + tid;
                const int kr  = idx >> 3;
                const int off = (idx & 7) * 8;
                kn[it] = *(const bf16x8*)(kb + (size_t)kcn * HS + idx * 8);
                vn[it] = *(const bf16x8*)(vTb + (size_t)kr * T_SEQ + kcn + off);
            }
        }

        // ---- compute chunk c from LDS (swapped: S^T tiles, k=rows q=cols) ----
        const int kc = c * 64;
#pragma unroll
        for (int st = 0; st < 2; ++st) {
            const int gk = kc + 32 * st;
            if (gk > q0 + 15) break;             // fully masked (wave-uniform)

            // K fragments: K[gk + tile*16 + col][d] — serve as A-operand (row=lane&15)
            bf16x8 b0 = *(const bf16x8*)&Kt[32 * st + col][quad * 8];
            bf16x8 b1 = *(const bf16x8*)&Kt[32 * st + col][32 + quad * 8];

            // lane (col=q, quad) gets S^T: P[q0+col][k = gk + tile*16 + quad*4 + r]
            float p0[4], p1[4];
            {
                f32x4 a4 = {0.f, 0.f, 0.f, 0.f};
                a4 = __builtin_amdgcn_mfma_f32_16x16x32_bf16(b0, qf0, a4, 0, 0, 0);
                a4 = __builtin_amdgcn_mfma_f32_16x16x32_bf16(b1, qf1, a4, 0, 0, 0);
#pragma unroll
                for (int i = 0; i < 4; ++i) p0[i] = fexp2(fmaf(a4[i], sc, -24.f));
            }
            const bool do1 = (gk + 16 <= q0 + 15);
            if (do1) {
                bf16x8 b2 = *(const bf16x8*)&Kt[32 * st + 16 + col][quad * 8];
                bf16x8 b3 = *(const bf16x8*)&Kt[32 * st + 16 + col][32 + quad * 8];
                f32x4 a4 = {0.f, 0.f, 0.f, 0.f};
                a4 = __builtin_amdgcn_mfma_f32_16x16x32_bf16(b2, qf0, a4, 0, 0, 0);
                a4 = __builtin_amdgcn_mfma_f32_16x16x32_bf16(b3, qf1, a4, 0, 0, 0);
#pragma unroll
                for (int i = 0; i < 4; ++i) p1[i] = fexp2(fmaf(a4[i], sc, -24.f));
            } else {
#pragma unroll
                for (int i = 0; i < 4; ++i) p1[i] = 0.f;
            }

            if (gk + 31 > q0) {                  // diagonal subtile: mask k > q
#pragma unroll
                for (int i = 0; i < 4; ++i)
                    if (gk + quad * 4 + i > q0 + col) p0[i] = 0.f;
                if (do1) {
#pragma unroll
                    for (int i = 0; i < 4; ++i)
                        if (gk + 16 + quad * 4 + i > q0 + col) p1[i] = 0.f;
                }
            }

            lsum += (p0[0] + p0[1]) + (p0[2] + p0[3]);
            if (do1) lsum += (p1[0] + p1[1]) + (p1[2] + p1[3]);

#if MFMA16_OK
            // PV directly from registers: A-frag of 16x16x16 is k=quad*4+j — matches.
            bf16x4 pa0 = {(bf16)p0[0], (bf16)p0[1], (bf16)p0[2], (bf16)p0[3]};
            s16x4 pa0s = bc4(pa0);
#pragma unroll
            for (int h = 0; h < 4; ++h) {
                bf16x4 vb = *(const bf16x4*)&Vt[h * 16 + col][32 * st + quad * 4];
                o[h] = __builtin_amdgcn_mfma_f32_16x16x16bf16_1k(
                    pa0s, bc4(vb), o[h], 0, 0, 0);
            }
            if (do1) {
                bf16x4 pa1 = {(bf16)p1[0], (bf16)p1[1], (bf16)p1[2], (bf16)p1[3]};
                s16x4 pa1s = bc4(pa1);
#pragma unroll
                for (int h = 0; h < 4; ++h) {
                    bf16x4 vb = *(const bf16x4*)&Vt[h * 16 + col][32 * st + 16 + quad * 4];
                    o[h] = __builtin_amdgcn_mfma_f32_16x16x16bf16_1k(
                        pa1s, bc4(vb), o[h], 0, 0, 0);
                }
            }
#else
            // fallback: [q][k] staging with vectorized b64 writes (wave-private,
            // in-order DS). Always write both halves (p1 zeroed when !do1).
            bf16x4 w0 = {(bf16)p0[0], (bf16)p0[1], (bf16)p0[2], (bf16)p0[3]};
            bf16x4 w1 = {(bf16)p1[0], (bf16)p1[1], (bf16)p1[2], (bf16)p1[3]};
            *(bf16x4*)&plds[wave][col][quad * 4]      = w0;
            *(bf16x4*)&plds[wave][col][16 + quad * 4] = w1;
            bf16x8 pa = *(const bf16x8*)&plds[wave][col][quad * 8];
#pragma unroll
            for (int h = 0; h < 4; ++h) {
                bf16x8 vb = *(const bf16x8*)&Vt[h * 16 + col][32 * st + quad * 8];
                o[h] = __builtin_amdgcn_mfma_f32_16x16x32_bf16(pa, vb, o[h], 0, 0, 0);
            }
#endif
        }
        __syncthreads();   // protect Kt/Vt before next write
    }

    // ---- epilogue ----
    // l: lane holds partial row-sum for q = q0+col; reduce across quads.
    lsum += __shfl_xor(lsum, 16, 64);
    lsum += __shfl_xor(lsum, 32, 64);
    if (quad == 0)
        l_parts[(size_t)jc * 16384 + (size_t)b * T_SEQ + q0 + col] = lsum;

    // O: C layout row=quad*4+i (q-local), col=lane&15 (n within h-group) — unchanged.
    const size_t rowbase = (size_t)b * T_SEQ + q0 + quad * 4;
    float* dst = (jc == 0) ? out : (o_parts + (size_t)(jc - 1) * 16384 * HS);
#pragma unroll
    for (int h = 0; h < 4; ++h)
#pragma unroll
        for (int i = 0; i < 4; ++i)
            dst[(rowbase + i) * HS + h * 16 + col] = o[h][i];
}

// ---------------------------------------------------------------------------
// Kernel 3: combine job partials and normalize: out = sum(O_j) / sum(l_j).
// ---------------------------------------------------------------------------
__global__ __launch_bounds__(256) void norm_kernel(
    float* __restrict__ out,
    const float* __restrict__ o_parts,  // [7][B*T][64]
    const float* __restrict__ l_parts)  // [8][B*T]
{
    const int i   = blockIdx.x * 256 + threadIdx.x;
    const int row = i >> 6;
    const int qb  = (row & 4095) >> 6;
    const int nj  = (qb >> 3) + 1;

    float s = out[i];
    float L = l_parts[row];
    for (int j = 1; j < nj; ++j) {
        s += o_parts[(size_t)(j - 1) * 1048576 + i];
        L += l_parts[(size_t)j * 16384 + row];
    }
    out[i] = s / L;
}

extern "C" void kernel_launch(void* const* d_in, const int* in_sizes, int n_in,
                              void* d_out, int out_size, void* d_ws, size_t ws_size,
                              hipStream_t stream) {
    const float* x  = (const float*)d_in[0];
    const float* Wk = (const float*)d_in[1];
    const float* Wv = (const float*)d_in[2];
    float* out = (float*)d_out;

    bf16* ws    = (bf16*)d_ws;
    bf16* wbf   = ws;                                    // 256 KB
    bf16* kmat  = ws + (size_t)128 * 1024;               // 2 MB
    bf16* qvmat = kmat + (size_t)16384 * 64;             // 2 MB
    bf16* qvT   = qvmat + (size_t)16384 * 64;            // 2 MB
    float* o_parts = (float*)(qvT + (size_t)16384 * 64); // 28 MB (slots 1-7)
    float* l_parts = o_parts + (size_t)7 * 16384 * 64;   // 512 KB

    wcast_kernel<<<64, 256, 0, stream>>>(Wk, Wv, wbf);
    proj_kernel<<<512, 256, 0, stream>>>(x, wbf, kmat, qvmat, qvT);
    attn_kernel<<<1152, 256, 0, stream>>>(kmat, qvmat, qvT, out, o_parts, l_parts);
    norm_kernel<<<4096, 256, 0, stream>>>(out, o_parts, l_parts);
}